// Round 1
// baseline (1062.975 us; speedup 1.0000x reference)
//
#include <hip/hip_runtime.h>

// DPO forward: out = log(2) + NLL(first half of batch).
// Round 3: FUSED GEMM — W stays fp32 in HBM; conversion to bf16 happens in
// the GEMM's B-staging (reg-stage: 4x dwordx4 + pack + swizzled ds_write_b64).
// Only X (8 MB) is pre-converted so A keeps the proven global_load_lds path.
// K-loop uses double-buffered LDS + raw s_barrier + counted vmcnt(4)
// (B prefetch depth 2 in regs, A depth 1 via global_load_lds) — VMEM is
// never drained in the main loop.

#define IGNORE_INDEX (-100)

typedef __attribute__((ext_vector_type(8))) short short8;
typedef __attribute__((ext_vector_type(4))) float f32x4;

constexpr int Ktot = 4096;
constexpr int Mtot = 1024;           // chosen-half rows only
constexpr int Vtot = 32000;
constexpr int NTILES = 250;          // 32000 / 128
constexpr long long NX = (long long)Mtot * Ktot;   // 4,194,304

__device__ __forceinline__ unsigned pack2_bf16(float a, float b) {
    unsigned ua = __float_as_uint(a);
    unsigned ub = __float_as_uint(b);
    ua += 0x7FFFu + ((ua >> 16) & 1u);
    ub += 0x7FFFu + ((ub >> 16) & 1u);
    return (ua >> 16) | (ub & 0xFFFF0000u);
}

__device__ __forceinline__ void load_lds_16(const void* g, void* l) {
    __builtin_amdgcn_global_load_lds(
        (const __attribute__((address_space(1))) unsigned int*)g,
        (__attribute__((address_space(3))) unsigned int*)l, 16, 0, 0);
}

// ---------------- X (chosen half) fp32 -> bf16: 16.8 MB read, ~8 us --------
__global__ __launch_bounds__(256)
void convert_x(const float* __restrict__ X, unsigned short* __restrict__ Xb)
{
    long long i = ((long long)blockIdx.x * 256 + threadIdx.x) * 8;
    float4 v0 = *(const float4*)(X + i);
    float4 v1 = *(const float4*)(X + i + 4);
    uint4 p;
    p.x = pack2_bf16(v0.x, v0.y);
    p.y = pack2_bf16(v0.z, v0.w);
    p.z = pack2_bf16(v1.x, v1.y);
    p.w = pack2_bf16(v1.z, v1.w);
    *(uint4*)(Xb + i) = p;
}

// ---------------- fused fp32-W bf16 GEMM + LSE ------------------------------
// One K-step: wait vmcnt(4) [retires B(t) regs + A(t) gload_lds];
// pack+ds_write B(t); issue A(t+1) gload_lds; issue B(t+2) reg loads;
// lgkmcnt(0)+barrier; ds_read frags + 16 MFMA; lgkmcnt(0)+barrier.
#define KSTEP(T, P, V0, V1, V2, V3, VMSTR, IA, IB) do {                         \
    asm volatile("s_waitcnt " VMSTR ::: "memory");                              \
    {                                                                           \
        uint2 q0, q1, q2, q3;                                                   \
        q0.x = pack2_bf16(V0.x, V0.y); q0.y = pack2_bf16(V0.z, V0.w);           \
        q1.x = pack2_bf16(V1.x, V1.y); q1.y = pack2_bf16(V1.z, V1.w);           \
        q2.x = pack2_bf16(V2.x, V2.y); q2.y = pack2_bf16(V2.z, V2.w);           \
        q3.x = pack2_bf16(V3.x, V3.y); q3.y = pack2_bf16(V3.z, V3.w);           \
        *(uint2*)&Bs[P][bw0 +    0] = q0;                                       \
        *(uint2*)&Bs[P][bw0 + 1024] = q1;                                       \
        *(uint2*)&Bs[P][bw0 + 2048] = q2;                                       \
        *(uint2*)&Bs[P][bw0 + 3072] = q3;                                       \
    }                                                                           \
    if (IA) {                                                                   \
        load_lds_16(aG + (size_t)((T) + 1) * 32,         &As[(P) ^ 1][aL]);     \
        load_lds_16(aG + (size_t)((T) + 1) * 32 + ahalf, &As[(P) ^ 1][2048 + aL]); \
    }                                                                           \
    asm volatile("" ::: "memory");  /* keep A-issues older than B-issues */     \
    if (IB) {                                                                   \
        V0 = *(const float4*)(bG + (size_t)((T) + 2) * 32 + 0 * brj);           \
        V1 = *(const float4*)(bG + (size_t)((T) + 2) * 32 + 1 * brj);           \
        V2 = *(const float4*)(bG + (size_t)((T) + 2) * 32 + 2 * brj);           \
        V3 = *(const float4*)(bG + (size_t)((T) + 2) * 32 + 3 * brj);           \
    }                                                                           \
    asm volatile("s_waitcnt lgkmcnt(0)" ::: "memory");                          \
    __builtin_amdgcn_s_barrier();                                               \
    asm volatile("" ::: "memory");                                              \
    {                                                                           \
        short8 af[4], bf[4];                                                    \
        _Pragma("unroll")                                                       \
        for (int mt = 0; mt < 4; mt++)                                          \
            af[mt] = *(const short8*)&As[P][(wm + mt * 16 + lq) * 32 + rseg];   \
        _Pragma("unroll")                                                       \
        for (int nt = 0; nt < 4; nt++)                                          \
            bf[nt] = *(const short8*)&Bs[P][(wn + nt * 16 + lq) * 32 + rseg];   \
        _Pragma("unroll")                                                       \
        for (int mt = 0; mt < 4; mt++)                                          \
            _Pragma("unroll")                                                   \
            for (int nt = 0; nt < 4; nt++)                                      \
                acc[mt][nt] = __builtin_amdgcn_mfma_f32_16x16x32_bf16(          \
                    af[mt], bf[nt], acc[mt][nt], 0, 0, 0);                      \
    }                                                                           \
    asm volatile("s_waitcnt lgkmcnt(0)" ::: "memory");                          \
    __builtin_amdgcn_s_barrier();                                               \
    asm volatile("" ::: "memory");                                              \
} while (0)

__global__ __launch_bounds__(256, 2)
void gemm_lse_fused(const unsigned short* __restrict__ Xb,
                    const float* __restrict__ W,
                    const int* __restrict__ tgt2,
                    float* __restrict__ ws_sum, float* __restrict__ ws_tl)
{
    // XCD swizzle: 8 M-tiles of one N-tile land consecutively on one XCD.
    int b = blockIdx.x;
    int xcd  = b & 7;
    int j    = b >> 3;
    int mt_b = j & 7;
    int grp  = j >> 3;
    int nt_b = xcd + 8 * grp;
    if (nt_b >= NTILES) return;

    const int m0 = mt_b * 128;
    const int n0 = nt_b * 128;

    __shared__ __align__(16) unsigned short As[2][128 * 32];  // 8 KB each
    __shared__ __align__(16) unsigned short Bs[2][128 * 32];  // 8 KB each

    const int tid = threadIdx.x;

    // --- A staging (global_load_lds, bf16, pre-swizzled source) ------------
    const int arow  = tid >> 2;                 // 0..63
    const int gsegA = (tid & 3) ^ (arow & 3);   // XOR-swizzled global segment
    const unsigned short* aG = Xb + (size_t)(m0 + arow) * Ktot + gsegA * 8;
    const int aL = tid * 8;                     // ushort idx; byte = tid*16 (wave-contig)
    constexpr size_t ahalf = (size_t)64 * Ktot; // rows 64..127

    // --- B staging (reg-stage fp32 W, pack, swizzled ds_write_b64) ---------
    const int tr = tid >> 3;                    // 0..31 (row within 32-row group)
    const int tg = tid & 7;                     // 8 threads cover one row's 32 floats
    const float* bG = W + (size_t)(n0 + tr) * Ktot + tg * 4;
    // LDS(row, s) holds global 16B-seg (s ^ (row&3)); our global seg g=(tg>>1),
    // half h=(tg&1)  ->  LDS seg s = g ^ (row&3)  (row&3 == tr&3 since j*32%4==0)
    const int bw0 = tr * 32 + (((tg >> 1) ^ (tr & 3)) * 8) + ((tg & 1) * 4);
    constexpr size_t brj = (size_t)32 * Ktot;   // +32 rows in floats

    // --- fragment read geometry (identical to verified round-2 kernel) -----
    const int lane = tid & 63;
    const int wid  = tid >> 6;
    const int wm = (wid >> 1) * 64, wn = (wid & 1) * 64;
    const int quad = lane >> 4, lq = lane & 15;
    const int rseg = (quad ^ (lq & 3)) * 8;     // un-swizzled read segment

    f32x4 acc[4][4];
#pragma unroll
    for (int i = 0; i < 4; i++)
#pragma unroll
        for (int jj = 0; jj < 4; jj++)
            acc[i][jj] = (f32x4){0.f, 0.f, 0.f, 0.f};

    // --- prologue: issue B(0) [4], A(0) [2], B(1) [4]  (FIFO order!) -------
    float4 va0, va1, va2, va3, vb0, vb1, vb2, vb3;
    va0 = *(const float4*)(bG + 0 * brj);
    va1 = *(const float4*)(bG + 1 * brj);
    va2 = *(const float4*)(bG + 2 * brj);
    va3 = *(const float4*)(bG + 3 * brj);
    asm volatile("" ::: "memory");
    load_lds_16(aG,         &As[0][aL]);
    load_lds_16(aG + ahalf, &As[0][2048 + aL]);
    asm volatile("" ::: "memory");
    vb0 = *(const float4*)(bG + 32 + 0 * brj);
    vb1 = *(const float4*)(bG + 32 + 1 * brj);
    vb2 = *(const float4*)(bG + 32 + 2 * brj);
    vb3 = *(const float4*)(bG + 32 + 3 * brj);
    asm volatile("" ::: "memory");

    // --- main loop: 128 K-tiles of 32; steady state keeps 10 VMEM in flight,
    //     waits to 4 (= the newest B group) each step. ----------------------
    for (int t = 0; t < 126; t += 2) {
        KSTEP(t,     0, va0, va1, va2, va3, "vmcnt(4)", true,  true);
        KSTEP(t + 1, 1, vb0, vb1, vb2, vb3, "vmcnt(4)", true,  true);
    }
    KSTEP(126, 0, va0, va1, va2, va3, "vmcnt(4)", true,  false);
    KSTEP(127, 1, vb0, vb1, vb2, vb3, "vmcnt(0)", false, false);

    // --- epilogue: per-row sum(exp) + target-logit scatter ------------------
    // C/D layout: col = lane&15, row = quad*4 + reg (verified round 1).
#pragma unroll
    for (int mt = 0; mt < 4; mt++) {
#pragma unroll
        for (int rr = 0; rr < 4; rr++) {
            float s = __expf(acc[mt][0][rr]) + __expf(acc[mt][1][rr]) +
                      __expf(acc[mt][2][rr]) + __expf(acc[mt][3][rr]);
            s += __shfl_xor(s, 1);
            s += __shfl_xor(s, 2);
            s += __shfl_xor(s, 4);
            s += __shfl_xor(s, 8);
            const int row = m0 + wm + mt * 16 + quad * 4 + rr;
            if (lq == 0) atomicAdd(&ws_sum[row], s);
            const int tv = tgt2[2 * row];
#pragma unroll
            for (int nt = 0; nt < 4; nt++) {
                const int col = n0 + wn + nt * 16 + lq;
                if (col == tv) ws_tl[row] = acc[mt][nt][rr];
            }
        }
    }
}

// ---------------- finalize --------------------------------------------------
__global__ void dpo_finalize(const float* __restrict__ ws_sum,
                             const float* __restrict__ ws_tl,
                             const int* __restrict__ tgt2,
                             float* __restrict__ out)
{
    __shared__ float sred[4];
    __shared__ float cred[4];
    float s = 0.f, c = 0.f;
    for (int i = threadIdx.x; i < 1024; i += 256) {
        const int tv = tgt2[2 * i];
        if (tv != IGNORE_INDEX) {
            s += ws_tl[i] - logf(ws_sum[i]);
            c += 1.f;
        }
    }
#pragma unroll
    for (int o = 32; o > 0; o >>= 1) {
        s += __shfl_down(s, o);
        c += __shfl_down(c, o);
    }
    const int wv = threadIdx.x >> 6, lane = threadIdx.x & 63;
    if (lane == 0) { sred[wv] = s; cred[wv] = c; }
    __syncthreads();
    if (threadIdx.x == 0) {
        const float st = sred[0] + sred[1] + sred[2] + sred[3];
        const float ct = cred[0] + cred[1] + cred[2] + cred[3];
        out[0] = 0.69314718055994531f - st / ct;
    }
}

extern "C" void kernel_launch(void* const* d_in, const int* in_sizes, int n_in,
                              void* d_out, int out_size, void* d_ws, size_t ws_size,
                              hipStream_t stream) {
    const float* X    = (const float*)d_in[0];   // (4,512,4096) fp32
    const int*   tgt2 = (const int*)d_in[1];     // (4,512) int64 as int pairs
    const float* W    = (const float*)d_in[2];   // (32000,4096) fp32
    float* out = (float*)d_out;

    float* ws_sum = (float*)d_ws;                          // [1024] f32
    float* ws_tl  = ws_sum + 1024;                         // [1024] f32
    unsigned short* Xb = (unsigned short*)(ws_tl + 1024);  // [1024*4096] bf16 (8.4 MB)

    hipMemsetAsync(d_ws, 0, 2048 * sizeof(float), stream);
    convert_x<<<(int)(NX / 8 / 256), 256, 0, stream>>>(X, Xb);   // 2048 blocks
    gemm_lse_fused<<<2048, 256, 0, stream>>>(Xb, W, tgt2, ws_sum, ws_tl);
    dpo_finalize<<<1, 256, 0, stream>>>(ws_sum, ws_tl, tgt2, out);
}

// Round 2
// 1001.996 us; speedup vs baseline: 1.0609x; 1.0609x over previous
//
#include <hip/hip_runtime.h>

// DPO forward: out = log(2) + NLL(first half of batch).
// Round 4: two-pass again (convert X+W -> bf16 in ws; proven ~165us), then a
// 256x256 8-phase counted-vmcnt GEMM (T2 swizzle + T3/T4 pipeline + T5
// setprio) replacing the ~900TF-capped m97-style 128^2 kernel.

#define IGNORE_INDEX (-100)

typedef __attribute__((ext_vector_type(8))) short short8;
typedef __attribute__((ext_vector_type(4))) float f32x4;

constexpr int Ktot = 4096;
constexpr int Mtot = 1024;           // chosen-half rows only
constexpr int Vtot = 32000;
constexpr long long NX = (long long)Mtot * Ktot;   // 4,194,304
constexpr long long NW = (long long)Vtot * Ktot;   // 131,072,000
constexpr int NWG = 4 * 125;         // (1024/256) * (32000/256) = 500

__device__ __forceinline__ unsigned pack2_bf16(float a, float b) {
    unsigned ua = __float_as_uint(a);
    unsigned ub = __float_as_uint(b);
    ua += 0x7FFFu + ((ua >> 16) & 1u);
    ub += 0x7FFFu + ((ub >> 16) & 1u);
    return (ua >> 16) | (ub & 0xFFFF0000u);
}

__device__ __forceinline__ void load_lds_16(const void* g, void* l) {
    __builtin_amdgcn_global_load_lds(
        (const __attribute__((address_space(1))) unsigned int*)g,
        (__attribute__((address_space(3))) unsigned int*)l, 16, 0, 0);
}

// ---------------- fp32 -> bf16 conversion (X first 1024 rows, then W) -------
__global__ __launch_bounds__(256)
void convert_to_bf16(const float* __restrict__ X, const float* __restrict__ W,
                     unsigned short* __restrict__ Xb, unsigned short* __restrict__ Wb)
{
    long long i = ((long long)blockIdx.x * 256 + threadIdx.x) * 8;
    const float* src;
    unsigned short* dst;
    long long off;
    if (i < NX) { src = X; dst = Xb; off = i; }
    else        { src = W; dst = Wb; off = i - NX; }
    float4 v0 = *(const float4*)(src + off);
    float4 v1 = *(const float4*)(src + off + 4);
    uint4 p;
    p.x = pack2_bf16(v0.x, v0.y);
    p.y = pack2_bf16(v0.z, v0.w);
    p.z = pack2_bf16(v1.x, v1.y);
    p.w = pack2_bf16(v1.z, v1.w);
    *(uint4*)(dst + off) = p;
}

// ---------------- 256^2 8-phase bf16 GEMM + fused LSE -----------------------
// LDS layout per operand: [2 buf][256 rows][64 cols] bf16; row = 128B = 8 segs
// of 16B. LDS[r][s] holds global seg (s ^ (r&7))  (T2 swizzle, applied on the
// pre-swizzled global source since global_load_lds dest must be linear).
// Staging: one half-tile (128 rows) per phase = 2 global_load_lds(16B)/thread.
// Waits: vmcnt(4) at end of phases 4 & 8 BEFORE the barrier (cross-wave safe).

#define STG(OP, BUF, HALF, TILE) do {                                          \
    const unsigned short* _s = s##OP##0 + (size_t)(HALF) * (128 * 4096)        \
                               + (size_t)(TILE) * 64;                          \
    unsigned short* _d = d##OP + (BUF) * 16384 + (HALF) * 8192;                \
    load_lds_16(_s,             _d);                                           \
    load_lds_16(_s + 64 * 4096, _d + 4096);                                    \
} while (0)

#define B1() do { __builtin_amdgcn_s_barrier();                                \
    asm volatile("s_waitcnt lgkmcnt(0)" ::: "memory");                         \
    __builtin_amdgcn_sched_barrier(0); } while (0)

#define B2() do { __builtin_amdgcn_s_barrier();                                \
    __builtin_amdgcn_sched_barrier(0); } while (0)

#define B2VM(S) do { asm volatile("s_waitcnt " S ::: "memory");                \
    __builtin_amdgcn_s_barrier();                                              \
    __builtin_amdgcn_sched_barrier(0); } while (0)

#define LD_AF(BUF, MTB) do { _Pragma("unroll")                                 \
    for (int _m = 0; _m < 4; _m++) {                                           \
        af[_m][0] = *(const short8*)&As[BUF][rowA + ((MTB) + _m) * 1024 + sw0];\
        af[_m][1] = *(const short8*)&As[BUF][rowA + ((MTB) + _m) * 1024 + sw1];\
    } } while (0)

#define LD_BF(BUF, NTB) do { _Pragma("unroll")                                 \
    for (int _n = 0; _n < 2; _n++) {                                           \
        bf[(NTB) + _n][0] = *(const short8*)&Bs[BUF][rowB + ((NTB) + _n) * 1024 + sw0]; \
        bf[(NTB) + _n][1] = *(const short8*)&Bs[BUF][rowB + ((NTB) + _n) * 1024 + sw1]; \
    } } while (0)

#define MF(MTB, NTB) do { __builtin_amdgcn_s_setprio(1);                       \
    _Pragma("unroll") for (int _m = 0; _m < 4; _m++)                           \
    _Pragma("unroll") for (int _n = 0; _n < 2; _n++)                           \
    _Pragma("unroll") for (int _k = 0; _k < 2; _k++)                           \
        acc[(MTB) + _m][(NTB) + _n] = __builtin_amdgcn_mfma_f32_16x16x32_bf16( \
            af[_m][_k], bf[(NTB) + _n][_k], acc[(MTB) + _m][(NTB) + _n], 0, 0, 0); \
    __builtin_amdgcn_s_setprio(0); } while (0)

// One iteration = K-tiles (2i from buf0, 2i+1 from buf1), 8 phases.
// Stages: ph1/2: A(t1)->buf1; ph3/4: B(t2)->buf0; ph5/6: A(t2)->buf0;
//         ph7/8: B(t3)->buf1.  (each half free one phase before its stage)
#define ITER(T1, T2, T3, FULL, VM4) do {                                       \
    /* ph1 */ LD_AF(0, 0); LD_BF(0, 0); STG(A, 1, 0, (T1));                    \
    B1(); MF(0, 0); B2();                                                      \
    /* ph2 */ LD_BF(0, 2); STG(A, 1, 1, (T1));                                 \
    B1(); MF(0, 2); B2();                                                      \
    /* ph3 */ LD_AF(0, 4); if (FULL) STG(B, 0, 0, (T2));                       \
    B1(); MF(4, 0); B2();                                                      \
    /* ph4 */ if (FULL) STG(B, 0, 1, (T2));                                    \
    B1(); MF(4, 2); B2VM(VM4);                                                 \
    /* ph5 */ LD_AF(1, 0); LD_BF(1, 0); if (FULL) STG(A, 0, 0, (T2));          \
    B1(); MF(0, 0); B2();                                                      \
    /* ph6 */ LD_BF(1, 2); if (FULL) STG(A, 0, 1, (T2));                       \
    B1(); MF(0, 2); B2();                                                      \
    /* ph7 */ LD_AF(1, 4); if (FULL) STG(B, 1, 0, (T3));                       \
    B1(); MF(4, 0); B2();                                                      \
    /* ph8 */ if (FULL) STG(B, 1, 1, (T3));                                    \
    B1(); MF(4, 2);                                                            \
    if (FULL) { B2VM("vmcnt(4)"); } else { B2(); }                             \
} while (0)

__global__ __launch_bounds__(512, 2)
void gemm_lse_8ph(const unsigned short* __restrict__ Xb,
                  const unsigned short* __restrict__ Wb,
                  const int* __restrict__ tgt2,
                  float* __restrict__ ws_sum, float* __restrict__ ws_tl)
{
    // Bijective XCD swizzle (nwg=500, 500%8!=0 -> m204 variant):
    // 4 consecutive wgids = 4 M-blocks of one N-panel -> same XCD L2.
    int b = blockIdx.x;
    int xcd = b & 7, bi = b >> 3;
    int wg = (xcd < 4 ? xcd * 63 : 252 + (xcd - 4) * 62) + bi;
    const int mt_b = wg & 3, nt_b = wg >> 2;
    const int m0 = mt_b * 256, n0 = nt_b * 256;

    __shared__ __align__(16) unsigned short As[2][256 * 64];  // 64 KB
    __shared__ __align__(16) unsigned short Bs[2][256 * 64];  // 64 KB

    const int tid = threadIdx.x;
    const int l = tid & 63, w = tid >> 6;

    // --- staging geometry: wave w covers rows w*8..w*8+7 of each 64-row rep;
    //     lane: row += l>>3, seg_l = l&7, global seg = (l&7) ^ ((l>>3)&7). ---
    const int srow = w * 8 + (l >> 3);
    const int gseg = (l & 7) ^ ((l >> 3) & 7);
    const unsigned short* sA0 = Xb + (size_t)(m0 + srow) * 4096 + gseg * 8;
    const unsigned short* sB0 = Wb + (size_t)(n0 + srow) * 4096 + gseg * 8;
    unsigned short* dA = &As[0][0] + tid * 8;   // byte off = tid*16 (wave-contig)
    unsigned short* dB = &Bs[0][0] + tid * 8;

    // --- fragment geometry (verified layout; 8-seg swizzle) -----------------
    const int wr = w >> 2, wc = w & 3;          // 2 x 4 wave grid
    const int quad = l >> 4, lq = l & 15;
    const int rowA = (wr * 128 + lq) * 64;
    const int rowB = (wc * 64 + lq) * 64;
    const int sw0 = ((0 + quad) ^ (lq & 7)) * 8;   // ks=0 seg
    const int sw1 = ((4 + quad) ^ (lq & 7)) * 8;   // ks=1 seg

    f32x4 acc[8][4];
#pragma unroll
    for (int i = 0; i < 8; i++)
#pragma unroll
        for (int j = 0; j < 4; j++)
            acc[i][j] = (f32x4){0.f, 0.f, 0.f, 0.f};

    short8 af[4][2];
    short8 bf[4][2];

    // --- prologue: T0 fully, then T1.B (12 loads, FIFO) ---------------------
    STG(A, 0, 0, 0); STG(A, 0, 1, 0);
    STG(B, 0, 0, 0); STG(B, 0, 1, 0);
    STG(B, 1, 0, 1); STG(B, 1, 1, 1);
    asm volatile("s_waitcnt vmcnt(4)" ::: "memory");   // T0 landed (T1.B in flight)
    __builtin_amdgcn_s_barrier();
    __builtin_amdgcn_sched_barrier(0);

    // --- main loop: 64 K-tiles of 64, 2 per iteration -----------------------
    for (int i = 0; i < 31; i++) {
        ITER(2 * i + 1, 2 * i + 2, 2 * i + 3, true, "vmcnt(4)");
    }
    ITER(63, 0, 0, false, "vmcnt(0)");   // peeled tail: stages only T63.A

    // --- epilogue: per-row sum(exp) + target-logit scatter ------------------
    // C/D layout: col = lane&15, row = quad*4 + reg (verified round 1).
#pragma unroll
    for (int mt = 0; mt < 8; mt++) {
#pragma unroll
        for (int rr = 0; rr < 4; rr++) {
            float s = __expf(acc[mt][0][rr]) + __expf(acc[mt][1][rr]) +
                      __expf(acc[mt][2][rr]) + __expf(acc[mt][3][rr]);
            s += __shfl_xor(s, 1);
            s += __shfl_xor(s, 2);
            s += __shfl_xor(s, 4);
            s += __shfl_xor(s, 8);
            const int row = m0 + wr * 128 + mt * 16 + quad * 4 + rr;
            if (lq == 0) atomicAdd(&ws_sum[row], s);
            const int tv = tgt2[2 * row];
#pragma unroll
            for (int nt = 0; nt < 4; nt++) {
                const int col = n0 + wc * 64 + nt * 16 + lq;
                if (col == tv) ws_tl[row] = acc[mt][nt][rr];
            }
        }
    }
}

// ---------------- round-1 fused fp32 kernel (fallback if ws too small) ------
__global__ __launch_bounds__(256, 2)
void dpo_gemm_lse_fb(const float* __restrict__ X, const float* __restrict__ W,
                     const int* __restrict__ tgt2,
                     float* __restrict__ ws_sum, float* __restrict__ ws_tl)
{
    int b = blockIdx.x;
    int xcd  = b & 7;
    int j    = b >> 3;
    int mt_b = j & 7;
    int grp  = j >> 3;
    int nt_b = xcd + 8 * grp;
    if (nt_b >= 250) return;

    const int m0 = mt_b * 128;
    const int n0 = nt_b * 128;

    __shared__ __align__(16) unsigned Asf[128 * 16];
    __shared__ __align__(16) unsigned Bsf[128 * 16];

    const int tid = threadIdx.x;
    const int r = tid >> 1, h = tid & 1;

    const float* aptr = X + (size_t)(m0 + r) * Ktot + h * 16;
    const float* bptr = W + (size_t)(n0 + r) * Ktot + h * 16;

    const int lane = tid & 63;
    const int wid  = tid >> 6;
    const int wm = (wid >> 1) * 64, wn = (wid & 1) * 64;
    const int quad = lane >> 4, lq = lane & 15;

    f32x4 acc[4][4];
#pragma unroll
    for (int i = 0; i < 4; i++)
#pragma unroll
        for (int jj = 0; jj < 4; jj++)
            acc[i][jj] = (f32x4){0.f, 0.f, 0.f, 0.f};

    for (int kk = 0; kk < Ktot; kk += 32) {
        const float4* ap = (const float4*)(aptr + kk);
        const float4* bp = (const float4*)(bptr + kk);
        float4 a0 = ap[0], a1 = ap[1], a2 = ap[2], a3 = ap[3];
        float4 b0 = bp[0], b1 = bp[1], b2 = bp[2], b3 = bp[3];

        __syncthreads();

        uint4 pa0, pa1, pb0, pb1;
        pa0.x = pack2_bf16(a0.x, a0.y); pa0.y = pack2_bf16(a0.z, a0.w);
        pa0.z = pack2_bf16(a1.x, a1.y); pa0.w = pack2_bf16(a1.z, a1.w);
        pa1.x = pack2_bf16(a2.x, a2.y); pa1.y = pack2_bf16(a2.z, a2.w);
        pa1.z = pack2_bf16(a3.x, a3.y); pa1.w = pack2_bf16(a3.z, a3.w);
        pb0.x = pack2_bf16(b0.x, b0.y); pb0.y = pack2_bf16(b0.z, b0.w);
        pb0.z = pack2_bf16(b1.x, b1.y); pb0.w = pack2_bf16(b1.z, b1.w);
        pb1.x = pack2_bf16(b2.x, b2.y); pb1.y = pack2_bf16(b2.z, b2.w);
        pb1.z = pack2_bf16(b3.x, b3.y); pb1.w = pack2_bf16(b3.z, b3.w);

        *(uint4*)&Asf[r * 16 + h * 8]     = pa0;
        *(uint4*)&Asf[r * 16 + h * 8 + 4] = pa1;
        *(uint4*)&Bsf[r * 16 + h * 8]     = pb0;
        *(uint4*)&Bsf[r * 16 + h * 8 + 4] = pb1;

        __syncthreads();

        short8 af[4], bfv[4];
#pragma unroll
        for (int mt = 0; mt < 4; mt++)
            af[mt] = __builtin_bit_cast(short8,
                *(const uint4*)&Asf[(wm + mt * 16 + lq) * 16 + quad * 4]);
#pragma unroll
        for (int nt = 0; nt < 4; nt++)
            bfv[nt] = __builtin_bit_cast(short8,
                *(const uint4*)&Bsf[(wn + nt * 16 + lq) * 16 + quad * 4]);

#pragma unroll
        for (int mt = 0; mt < 4; mt++)
#pragma unroll
            for (int nt = 0; nt < 4; nt++)
                acc[mt][nt] = __builtin_amdgcn_mfma_f32_16x16x32_bf16(
                    af[mt], bfv[nt], acc[mt][nt], 0, 0, 0);
    }

#pragma unroll
    for (int mt = 0; mt < 4; mt++) {
#pragma unroll
        for (int rr = 0; rr < 4; rr++) {
            float s = __expf(acc[mt][0][rr]) + __expf(acc[mt][1][rr]) +
                      __expf(acc[mt][2][rr]) + __expf(acc[mt][3][rr]);
            s += __shfl_xor(s, 1);
            s += __shfl_xor(s, 2);
            s += __shfl_xor(s, 4);
            s += __shfl_xor(s, 8);
            const int row = m0 + wm + mt * 16 + quad * 4 + rr;
            if (lq == 0) atomicAdd(&ws_sum[row], s);
            const int tv = tgt2[2 * row];
#pragma unroll
            for (int nt = 0; nt < 4; nt++) {
                const int col = n0 + wn + nt * 16 + lq;
                if (col == tv) ws_tl[row] = acc[mt][nt][rr];
            }
        }
    }
}

// ---------------- finalize --------------------------------------------------
__global__ void dpo_finalize(const float* __restrict__ ws_sum,
                             const float* __restrict__ ws_tl,
                             const int* __restrict__ tgt2,
                             float* __restrict__ out)
{
    __shared__ float sred[4];
    __shared__ float cred[4];
    float s = 0.f, c = 0.f;
    for (int i = threadIdx.x; i < 1024; i += 256) {
        const int tv = tgt2[2 * i];
        if (tv != IGNORE_INDEX) {
            s += ws_tl[i] - logf(ws_sum[i]);
            c += 1.f;
        }
    }
#pragma unroll
    for (int o = 32; o > 0; o >>= 1) {
        s += __shfl_down(s, o);
        c += __shfl_down(c, o);
    }
    const int wv = threadIdx.x >> 6, lane = threadIdx.x & 63;
    if (lane == 0) { sred[wv] = s; cred[wv] = c; }
    __syncthreads();
    if (threadIdx.x == 0) {
        const float st = sred[0] + sred[1] + sred[2] + sred[3];
        const float ct = cred[0] + cred[1] + cred[2] + cred[3];
        out[0] = 0.69314718055994531f - st / ct;
    }
}

extern "C" void kernel_launch(void* const* d_in, const int* in_sizes, int n_in,
                              void* d_out, int out_size, void* d_ws, size_t ws_size,
                              hipStream_t stream) {
    const float* X    = (const float*)d_in[0];   // (4,512,4096) fp32
    const int*   tgt2 = (const int*)d_in[1];     // (4,512) int64 as int pairs
    const float* W    = (const float*)d_in[2];   // (32000,4096) fp32
    float* out = (float*)d_out;

    float* ws_sum = (float*)d_ws;                          // [1024] f32
    float* ws_tl  = ws_sum + 1024;                         // [1024] f32
    unsigned short* Xb = (unsigned short*)(ws_tl + 1024);  // [1024*4096] bf16
    unsigned short* Wb = Xb + NX;                          // [32000*4096] bf16

    const size_t need = 2048 * sizeof(float) + (size_t)(NX + NW) * 2;

    hipMemsetAsync(d_ws, 0, 2048 * sizeof(float), stream);
    if (ws_size >= need) {
        const int conv_blocks = (int)((NX + NW) / 8 / 256);  // exact: 66048
        convert_to_bf16<<<conv_blocks, 256, 0, stream>>>(X, W, Xb, Wb);
        gemm_lse_8ph<<<NWG, 512, 0, stream>>>(Xb, Wb, tgt2, ws_sum, ws_tl);
    } else {
        dpo_gemm_lse_fb<<<2048, 256, 0, stream>>>(X, W, tgt2, ws_sum, ws_tl);
    }
    dpo_finalize<<<1, 256, 0, stream>>>(ws_sum, ws_tl, tgt2, out);
}